// Round 1
// baseline (1375.182 us; speedup 1.0000x reference)
//
#include <hip/hip_runtime.h>

#define D 64

// Fused 2-layer MLP per node: out[n,:] = relu( relu(x[n,:]@A + a) @ B + b )
// One wave (64 lanes) per node; lane j owns output column j.
// Weights staged in LDS; input row broadcast via __shfl.
__global__ __launch_bounds__(256) void mlp2_kernel(
    const float* __restrict__ x,
    const float* __restrict__ A, const float* __restrict__ a,
    const float* __restrict__ B, const float* __restrict__ b,
    float* __restrict__ out, int n_nodes)
{
    __shared__ float sA[D * D];
    __shared__ float sB[D * D];
    __shared__ float sa[D];
    __shared__ float sb[D];

    // Cooperative weight staging (vectorized): 4096 floats each = 1024 float4
    for (int i = threadIdx.x; i < D * D / 4; i += blockDim.x) {
        ((float4*)sA)[i] = ((const float4*)A)[i];
        ((float4*)sB)[i] = ((const float4*)B)[i];
    }
    if (threadIdx.x < D) {
        sa[threadIdx.x] = a[threadIdx.x];
        sb[threadIdx.x] = b[threadIdx.x];
    }
    __syncthreads();

    const int lane = threadIdx.x & 63;
    const int wave = threadIdx.x >> 6;
    const int wavesPerBlock = blockDim.x >> 6;
    const int globalWave = blockIdx.x * wavesPerBlock + wave;
    const int totalWaves = gridDim.x * wavesPerBlock;

    for (int n = globalWave; n < n_nodes; n += totalWaves) {
        float v = x[(size_t)n * D + lane];   // coalesced 256B per wave

        float h = sa[lane];
        #pragma unroll
        for (int k = 0; k < D; ++k) {
            float xv = __shfl(v, k, 64);
            h = fmaf(xv, sA[k * D + lane], h);   // stride-1 LDS: 2-way alias, free
        }
        h = fmaxf(h, 0.f);

        float o = sb[lane];
        #pragma unroll
        for (int k = 0; k < D; ++k) {
            float hv = __shfl(h, k, 64);
            o = fmaf(hv, sB[k * D + lane], o);
        }
        o = fmaxf(o, 0.f);

        out[(size_t)n * D + lane] = o;
    }
}

// Scatter-add: z[dst[e], :] += msg[src[e], :]. 16 threads per edge, float4 each.
__global__ __launch_bounds__(256) void scatter_kernel(
    const float* __restrict__ msg,
    const int* __restrict__ src, const int* __restrict__ dst,
    float* __restrict__ z, int n_edges)
{
    long long t = (long long)blockIdx.x * blockDim.x + threadIdx.x;
    int e = (int)(t >> 4);
    if (e >= n_edges) return;
    int d4 = ((int)t & 15) * 4;

    int s = src[e];
    int d = dst[e];
    float4 v = *(const float4*)(msg + (size_t)s * D + d4);
    float* zp = z + (size_t)d * D + d4;
    atomicAdd(zp + 0, v.x);
    atomicAdd(zp + 1, v.y);
    atomicAdd(zp + 2, v.z);
    atomicAdd(zp + 3, v.w);
}

extern "C" void kernel_launch(void* const* d_in, const int* in_sizes, int n_in,
                              void* d_out, int out_size, void* d_ws, size_t ws_size,
                              hipStream_t stream) {
    const float* y  = (const float*)d_in[0];
    const int*  src = (const int*) d_in[1];
    const int*  dst = (const int*) d_in[2];
    const float* W1 = (const float*)d_in[3];
    const float* b1 = (const float*)d_in[4];
    const float* W2 = (const float*)d_in[5];
    const float* b2 = (const float*)d_in[6];
    const float* U1 = (const float*)d_in[7];
    const float* c1 = (const float*)d_in[8];
    const float* U2 = (const float*)d_in[9];
    const float* c2 = (const float*)d_in[10];

    const int N = in_sizes[0] / D;   // 50000
    const int E = in_sizes[1];       // 1250000

    float* msg = (float*)d_ws;               // N*D floats = 12.8 MB
    float* z   = msg + (size_t)N * D;        // N*D floats = 12.8 MB

    // z must be zeroed (ws is poisoned 0xAA before every call)
    hipMemsetAsync(z, 0, (size_t)N * D * sizeof(float), stream);

    // 1) per-node message MLP: msg = relu(relu(y@W1+b1)@W2+b2)
    const int wavesPerBlock = 4;
    int grid1 = (N + wavesPerBlock - 1) / wavesPerBlock;   // one wave per node
    mlp2_kernel<<<grid1, 256, 0, stream>>>(y, W1, b1, W2, b2, msg, N);

    // 2) scatter-add messages into z
    long long total = (long long)E * 16;
    int grid2 = (int)((total + 255) / 256);
    scatter_kernel<<<grid2, 256, 0, stream>>>(msg, src, dst, z, E);

    // 3) node update MLP: h = relu(relu(z@U1+c1)@U2+c2)
    mlp2_kernel<<<grid1, 256, 0, stream>>>(z, U1, c1, U2, c2, (float*)d_out, N);
}

// Round 2
// 805.773 us; speedup vs baseline: 1.7067x; 1.7067x over previous
//
#include <hip/hip_runtime.h>

#define D 64
#define NBLK_WAVES 4

// ---------------------------------------------------------------------------
// Fused 2-layer MLP per node: out[n,:] = relu( relu(x[n,:]@A + a) @ B + b )
// One wave per node; lane j owns output column j. Weights in LDS, input row
// broadcast via __shfl.
// ---------------------------------------------------------------------------
__global__ __launch_bounds__(256) void mlp2_kernel(
    const float* __restrict__ x,
    const float* __restrict__ A, const float* __restrict__ a,
    const float* __restrict__ B, const float* __restrict__ b,
    float* __restrict__ out, int n_nodes)
{
    __shared__ float sA[D * D];
    __shared__ float sB[D * D];
    __shared__ float sa[D];
    __shared__ float sb[D];

    for (int i = threadIdx.x; i < D * D / 4; i += blockDim.x) {
        ((float4*)sA)[i] = ((const float4*)A)[i];
        ((float4*)sB)[i] = ((const float4*)B)[i];
    }
    if (threadIdx.x < D) {
        sa[threadIdx.x] = a[threadIdx.x];
        sb[threadIdx.x] = b[threadIdx.x];
    }
    __syncthreads();

    const int lane = threadIdx.x & 63;
    const int wave = threadIdx.x >> 6;
    const int globalWave = blockIdx.x * NBLK_WAVES + wave;
    const int totalWaves = gridDim.x * NBLK_WAVES;

    for (int n = globalWave; n < n_nodes; n += totalWaves) {
        float v = x[(size_t)n * D + lane];

        float h = sa[lane];
        #pragma unroll
        for (int k = 0; k < D; ++k) {
            float xv = __shfl(v, k, 64);
            h = fmaf(xv, sA[k * D + lane], h);
        }
        h = fmaxf(h, 0.f);

        float o = sb[lane];
        #pragma unroll
        for (int k = 0; k < D; ++k) {
            float hv = __shfl(h, k, 64);
            o = fmaf(hv, sB[k * D + lane], o);
        }
        o = fmaxf(o, 0.f);

        out[(size_t)n * D + lane] = o;
    }
}

// ---------------------------------------------------------------------------
// CSR build step 1: histogram of dst
// ---------------------------------------------------------------------------
__global__ __launch_bounds__(256) void hist_kernel(
    const int* __restrict__ dst, int* __restrict__ counts, int n_edges)
{
    int i = blockIdx.x * blockDim.x + threadIdx.x;
    if (i < n_edges) atomicAdd(&counts[dst[i]], 1);
}

// ---------------------------------------------------------------------------
// CSR build step 2: exclusive scan of counts -> offsets[N+1], cursor[N]
// Single block of 1024 threads; each thread owns a contiguous chunk.
// ---------------------------------------------------------------------------
__global__ __launch_bounds__(1024) void scan_kernel(
    const int* __restrict__ counts, int* __restrict__ offsets,
    int* __restrict__ cursor, int n)
{
    __shared__ int partial[1024];
    const int t = threadIdx.x;
    const int chunk = (n + 1023) / 1024;
    const int begin = t * chunk;
    const int end = min(begin + chunk, n);

    int s = 0;
    for (int i = begin; i < end; ++i) s += counts[i];
    partial[t] = s;
    __syncthreads();

    // inclusive Hillis-Steele scan over 1024 partials
    for (int off = 1; off < 1024; off <<= 1) {
        int v = partial[t];
        int add = (t >= off) ? partial[t - off] : 0;
        __syncthreads();
        partial[t] = v + add;
        __syncthreads();
    }

    int run = (t == 0) ? 0 : partial[t - 1];   // exclusive base
    for (int i = begin; i < end; ++i) {
        int c = counts[i];
        offsets[i] = run;
        cursor[i] = run;
        run += c;
    }
    if (t == 1023) offsets[n] = partial[1023];  // total = E
}

// ---------------------------------------------------------------------------
// CSR build step 3: scatter src into dst-sorted order
// ---------------------------------------------------------------------------
__global__ __launch_bounds__(256) void perm_kernel(
    const int* __restrict__ src, const int* __restrict__ dst,
    int* __restrict__ cursor, int* __restrict__ sorted_src, int n_edges)
{
    int i = blockIdx.x * blockDim.x + threadIdx.x;
    if (i < n_edges) {
        int p = atomicAdd(&cursor[dst[i]], 1);
        sorted_src[p] = src[i];
    }
}

// ---------------------------------------------------------------------------
// Fused: z[n] = sum_{e in CSR row n} msg[sorted_src[e]]  (registers only),
// then out[n] = relu(relu(z@U1+c1)@U2+c2). One wave per node.
// ---------------------------------------------------------------------------
__global__ __launch_bounds__(256) void gather_mlp_kernel(
    const float* __restrict__ msg,
    const int* __restrict__ offsets, const int* __restrict__ sorted_src,
    const float* __restrict__ A, const float* __restrict__ a,
    const float* __restrict__ B, const float* __restrict__ b,
    float* __restrict__ out, int n_nodes)
{
    __shared__ float sA[D * D];
    __shared__ float sB[D * D];
    __shared__ float sa[D];
    __shared__ float sb[D];

    for (int i = threadIdx.x; i < D * D / 4; i += blockDim.x) {
        ((float4*)sA)[i] = ((const float4*)A)[i];
        ((float4*)sB)[i] = ((const float4*)B)[i];
    }
    if (threadIdx.x < D) {
        sa[threadIdx.x] = a[threadIdx.x];
        sb[threadIdx.x] = b[threadIdx.x];
    }
    __syncthreads();

    const int lane = threadIdx.x & 63;
    const int wave = threadIdx.x >> 6;
    const int globalWave = blockIdx.x * NBLK_WAVES + wave;
    const int totalWaves = gridDim.x * NBLK_WAVES;

    for (int n = globalWave; n < n_nodes; n += totalWaves) {
        const int beg = offsets[n];
        const int end = offsets[n + 1];

        float acc = 0.f;
        for (int i = beg; i < end; ++i) {
            int s = __builtin_amdgcn_readfirstlane(sorted_src[i]);  // wave-uniform
            acc += msg[(size_t)s * D + lane];    // coalesced 256B row, L2/L3-hot
        }

        float h = sa[lane];
        #pragma unroll
        for (int k = 0; k < D; ++k) {
            float zv = __shfl(acc, k, 64);
            h = fmaf(zv, sA[k * D + lane], h);
        }
        h = fmaxf(h, 0.f);

        float o = sb[lane];
        #pragma unroll
        for (int k = 0; k < D; ++k) {
            float hv = __shfl(h, k, 64);
            o = fmaf(hv, sB[k * D + lane], o);
        }
        o = fmaxf(o, 0.f);

        out[(size_t)n * D + lane] = o;
    }
}

extern "C" void kernel_launch(void* const* d_in, const int* in_sizes, int n_in,
                              void* d_out, int out_size, void* d_ws, size_t ws_size,
                              hipStream_t stream) {
    const float* y  = (const float*)d_in[0];
    const int*  src = (const int*) d_in[1];
    const int*  dst = (const int*) d_in[2];
    const float* W1 = (const float*)d_in[3];
    const float* b1 = (const float*)d_in[4];
    const float* W2 = (const float*)d_in[5];
    const float* b2 = (const float*)d_in[6];
    const float* U1 = (const float*)d_in[7];
    const float* c1 = (const float*)d_in[8];
    const float* U2 = (const float*)d_in[9];
    const float* c2 = (const float*)d_in[10];

    const int N = in_sizes[0] / D;   // 50000
    const int E = in_sizes[1];       // 1250000

    // Workspace layout (all 4-byte types):
    //   msg        : N*D floats (12.8 MB)
    //   sorted_src : E ints     (5 MB)
    //   counts     : N ints
    //   offsets    : N+1 ints
    //   cursor     : N ints
    float* msg        = (float*)d_ws;
    int*   sorted_src = (int*)(msg + (size_t)N * D);
    int*   counts     = sorted_src + E;
    int*   offsets    = counts + N;
    int*   cursor     = offsets + (N + 1);

    // counts must start at zero (ws is poisoned 0xAA each call)
    hipMemsetAsync(counts, 0, (size_t)N * sizeof(int), stream);

    // CSR build
    int gridE = (E + 255) / 256;
    hist_kernel<<<gridE, 256, 0, stream>>>(dst, counts, E);
    scan_kernel<<<1, 1024, 0, stream>>>(counts, offsets, cursor, N);
    perm_kernel<<<gridE, 256, 0, stream>>>(src, dst, cursor, sorted_src, E);

    // per-node message MLP (independent of CSR build)
    int gridN = (N + NBLK_WAVES - 1) / NBLK_WAVES;
    mlp2_kernel<<<gridN, 256, 0, stream>>>(y, W1, b1, W2, b2, msg, N);

    // fused gather segment-sum + update MLP
    gather_mlp_kernel<<<gridN, 256, 0, stream>>>(msg, offsets, sorted_src,
                                                 U1, c1, U2, c2,
                                                 (float*)d_out, N);
}

// Round 3
// 351.581 us; speedup vs baseline: 3.9114x; 2.2919x over previous
//
#include <hip/hip_runtime.h>

#define D 64

__device__ __forceinline__ float lane_bcast_f(float v, int k) {
    return __int_as_float(__builtin_amdgcn_readlane(__float_as_int(v), k));
}

// ---------------------------------------------------------------------------
// 2-layer MLP, weights resident in VGPRs (lane j holds column j of A and B),
// input row broadcast via v_readlane (pure VALU — zero LDS traffic).
// One wave per node per iteration, grid-stride, next-row prefetch.
// ---------------------------------------------------------------------------
__global__ __launch_bounds__(256) void mlp2_reg_kernel(
    const float* __restrict__ x,
    const float* __restrict__ A, const float* __restrict__ a,
    const float* __restrict__ B, const float* __restrict__ b,
    float* __restrict__ out, int n_nodes)
{
    const int lane = threadIdx.x & 63;
    const int wave = threadIdx.x >> 6;
    const int gw = blockIdx.x * (blockDim.x >> 6) + wave;
    const int tw = gridDim.x * (blockDim.x >> 6);

    float wA[D], wB[D];
    #pragma unroll
    for (int k = 0; k < D; ++k) wA[k] = A[k * D + lane];   // coalesced, L1-hot
    #pragma unroll
    for (int k = 0; k < D; ++k) wB[k] = B[k * D + lane];
    const float ba = a[lane], bb = b[lane];

    int n = gw;
    if (n >= n_nodes) return;
    float v = x[(size_t)n * D + lane];

    for (; n < n_nodes; n += tw) {
        const int nn = n + tw;
        float vnext = 0.f;
        if (nn < n_nodes) vnext = x[(size_t)nn * D + lane];   // prefetch

        float h = ba;
        #pragma unroll
        for (int k = 0; k < D; ++k) h = fmaf(lane_bcast_f(v, k), wA[k], h);
        h = fmaxf(h, 0.f);

        float o = bb;
        #pragma unroll
        for (int k = 0; k < D; ++k) o = fmaf(lane_bcast_f(h, k), wB[k], o);
        o = fmaxf(o, 0.f);

        out[(size_t)n * D + lane] = o;
        v = vnext;
    }
}

// ---------------------------------------------------------------------------
// CSR build: histogram of dst
// ---------------------------------------------------------------------------
__global__ __launch_bounds__(256) void hist_kernel(
    const int* __restrict__ dst, int* __restrict__ counts, int n_edges)
{
    int i = blockIdx.x * blockDim.x + threadIdx.x;
    if (i < n_edges) atomicAdd(&counts[dst[i]], 1);
}

// ---------------------------------------------------------------------------
// Scan phase A: per-block (256-elem chunk) sums
// ---------------------------------------------------------------------------
__global__ __launch_bounds__(256) void scanA_kernel(
    const int* __restrict__ counts, int* __restrict__ bsum, int n)
{
    __shared__ int red[4];
    int i = blockIdx.x * 256 + threadIdx.x;
    int v = (i < n) ? counts[i] : 0;
    #pragma unroll
    for (int off = 32; off > 0; off >>= 1) v += __shfl_down(v, off, 64);
    if ((threadIdx.x & 63) == 0) red[threadIdx.x >> 6] = v;
    __syncthreads();
    if (threadIdx.x == 0) bsum[blockIdx.x] = red[0] + red[1] + red[2] + red[3];
}

// ---------------------------------------------------------------------------
// Scan phase B: exclusive scan of block sums (nb <= 256), single block
// ---------------------------------------------------------------------------
__global__ __launch_bounds__(256) void scanB_kernel(int* __restrict__ bsum, int nb)
{
    __shared__ int tmp[256];
    const int t = threadIdx.x;
    int v = (t < nb) ? bsum[t] : 0;
    int x = v;
    tmp[t] = x;
    __syncthreads();
    #pragma unroll
    for (int off = 1; off < 256; off <<= 1) {
        int add = (t >= off) ? tmp[t - off] : 0;
        __syncthreads();
        x += add;
        tmp[t] = x;
        __syncthreads();
    }
    if (t < nb) bsum[t] = x - v;   // exclusive
}

// ---------------------------------------------------------------------------
// Scan phase C: per-block exclusive scan + base -> offsets, cursor
// ---------------------------------------------------------------------------
__global__ __launch_bounds__(256) void scanC_kernel(
    const int* __restrict__ counts, const int* __restrict__ bsum,
    int* __restrict__ offsets, int* __restrict__ cursor, int n, int n_edges)
{
    __shared__ int tmp[256];
    const int t = threadIdx.x;
    const int i = blockIdx.x * 256 + t;
    int v = (i < n) ? counts[i] : 0;
    int x = v;
    tmp[t] = x;
    __syncthreads();
    #pragma unroll
    for (int off = 1; off < 256; off <<= 1) {
        int add = (t >= off) ? tmp[t - off] : 0;
        __syncthreads();
        x += add;
        tmp[t] = x;
        __syncthreads();
    }
    int excl = x - v + bsum[blockIdx.x];
    if (i < n) { offsets[i] = excl; cursor[i] = excl; }
    if (blockIdx.x == 0 && t == 0) offsets[n] = n_edges;
}

// ---------------------------------------------------------------------------
// CSR build: scatter src into dst-sorted order
// ---------------------------------------------------------------------------
__global__ __launch_bounds__(256) void perm_kernel(
    const int* __restrict__ src, const int* __restrict__ dst,
    int* __restrict__ cursor, int* __restrict__ sorted_src, int n_edges)
{
    int i = blockIdx.x * blockDim.x + threadIdx.x;
    if (i < n_edges) {
        int p = atomicAdd(&cursor[dst[i]], 1);
        sorted_src[p] = src[i];
    }
}

// ---------------------------------------------------------------------------
// Fused gather segment-sum + 2-layer MLP (weights in VGPRs).
// Gather: 64 edge indices per coalesced batch load, v_readlane broadcast,
// 8 independent row loads in flight.
// ---------------------------------------------------------------------------
__global__ __launch_bounds__(256) void gather_mlp_kernel(
    const float* __restrict__ msg,
    const int* __restrict__ offsets, const int* __restrict__ sorted_src,
    const float* __restrict__ A, const float* __restrict__ a,
    const float* __restrict__ B, const float* __restrict__ b,
    float* __restrict__ out, int n_nodes)
{
    const int lane = threadIdx.x & 63;
    const int wave = threadIdx.x >> 6;
    const int gw = blockIdx.x * (blockDim.x >> 6) + wave;
    const int tw = gridDim.x * (blockDim.x >> 6);

    float wA[D], wB[D];
    #pragma unroll
    for (int k = 0; k < D; ++k) wA[k] = A[k * D + lane];
    #pragma unroll
    for (int k = 0; k < D; ++k) wB[k] = B[k * D + lane];
    const float ba = a[lane], bb = b[lane];

    for (int n = gw; n < n_nodes; n += tw) {
        const int beg = offsets[n];
        const int end = offsets[n + 1];

        float acc0 = 0.f, acc1 = 0.f, acc2 = 0.f, acc3 = 0.f;
        float acc4 = 0.f, acc5 = 0.f, acc6 = 0.f, acc7 = 0.f;

        for (int base = beg; base < end; base += 64) {
            const int m = min(64, end - base);
            int idx = 0;
            if (lane < m) idx = sorted_src[base + lane];  // one coalesced load

            int k = 0;
            for (; k + 8 <= m; k += 8) {
                int s0 = __builtin_amdgcn_readlane(idx, k + 0);
                int s1 = __builtin_amdgcn_readlane(idx, k + 1);
                int s2 = __builtin_amdgcn_readlane(idx, k + 2);
                int s3 = __builtin_amdgcn_readlane(idx, k + 3);
                int s4 = __builtin_amdgcn_readlane(idx, k + 4);
                int s5 = __builtin_amdgcn_readlane(idx, k + 5);
                int s6 = __builtin_amdgcn_readlane(idx, k + 6);
                int s7 = __builtin_amdgcn_readlane(idx, k + 7);
                acc0 += msg[(size_t)s0 * D + lane];
                acc1 += msg[(size_t)s1 * D + lane];
                acc2 += msg[(size_t)s2 * D + lane];
                acc3 += msg[(size_t)s3 * D + lane];
                acc4 += msg[(size_t)s4 * D + lane];
                acc5 += msg[(size_t)s5 * D + lane];
                acc6 += msg[(size_t)s6 * D + lane];
                acc7 += msg[(size_t)s7 * D + lane];
            }
            for (; k < m; ++k) {
                int s = __builtin_amdgcn_readlane(idx, k);
                acc0 += msg[(size_t)s * D + lane];
            }
        }
        float z = ((acc0 + acc1) + (acc2 + acc3)) + ((acc4 + acc5) + (acc6 + acc7));

        float h = ba;
        #pragma unroll
        for (int k = 0; k < D; ++k) h = fmaf(lane_bcast_f(z, k), wA[k], h);
        h = fmaxf(h, 0.f);

        float o = bb;
        #pragma unroll
        for (int k = 0; k < D; ++k) o = fmaf(lane_bcast_f(h, k), wB[k], o);
        o = fmaxf(o, 0.f);

        out[(size_t)n * D + lane] = o;
    }
}

extern "C" void kernel_launch(void* const* d_in, const int* in_sizes, int n_in,
                              void* d_out, int out_size, void* d_ws, size_t ws_size,
                              hipStream_t stream) {
    const float* y  = (const float*)d_in[0];
    const int*  src = (const int*) d_in[1];
    const int*  dst = (const int*) d_in[2];
    const float* W1 = (const float*)d_in[3];
    const float* b1 = (const float*)d_in[4];
    const float* W2 = (const float*)d_in[5];
    const float* b2 = (const float*)d_in[6];
    const float* U1 = (const float*)d_in[7];
    const float* c1 = (const float*)d_in[8];
    const float* U2 = (const float*)d_in[9];
    const float* c2 = (const float*)d_in[10];

    const int N = in_sizes[0] / D;   // 50000
    const int E = in_sizes[1];       // 1250000

    // Workspace layout (4-byte types):
    //   msg        : N*D floats (12.8 MB)
    //   sorted_src : E ints     (5 MB)
    //   counts     : N ints
    //   offsets    : N+1 ints
    //   cursor     : N ints
    //   bsum       : 256 ints
    float* msg        = (float*)d_ws;
    int*   sorted_src = (int*)(msg + (size_t)N * D);
    int*   counts     = sorted_src + E;
    int*   offsets    = counts + N;
    int*   cursor     = offsets + (N + 1);
    int*   bsum       = cursor + N;

    const int NB = (N + 255) / 256;          // 196 scan blocks

    hipMemsetAsync(counts, 0, (size_t)N * sizeof(int), stream);

    // per-node message MLP (independent of CSR chain)
    mlp2_reg_kernel<<<1024, 256, 0, stream>>>(y, W1, b1, W2, b2, msg, N);

    // CSR build
    int gridE = (E + 255) / 256;
    hist_kernel<<<gridE, 256, 0, stream>>>(dst, counts, E);
    scanA_kernel<<<NB, 256, 0, stream>>>(counts, bsum, N);
    scanB_kernel<<<1, 256, 0, stream>>>(bsum, NB);
    scanC_kernel<<<NB, 256, 0, stream>>>(counts, bsum, offsets, cursor, N, E);
    perm_kernel<<<gridE, 256, 0, stream>>>(src, dst, cursor, sorted_src, E);

    // fused gather segment-sum + update MLP
    gather_mlp_kernel<<<2048, 256, 0, stream>>>(msg, offsets, sorted_src,
                                                U1, c1, U2, c2,
                                                (float*)d_out, N);
}

// Round 4
// 330.553 us; speedup vs baseline: 4.1602x; 1.0636x over previous
//
#include <hip/hip_runtime.h>

#define D 64
#define MLP_BLOCKS 1024

__device__ __forceinline__ float lane_bcast_f(float v, int k) {
    return __int_as_float(__builtin_amdgcn_readlane(__float_as_int(v), k));
}

// ---------------------------------------------------------------------------
// MLP device body: out[n,:] = relu( relu(x[n,:]@A + a) @ B + b ), one wave
// per node, weights in VGPRs (lane j owns column j), v_readlane broadcast.
// ---------------------------------------------------------------------------
__device__ __forceinline__ void mlp2_body(
    const float* __restrict__ x,
    const float* __restrict__ A, const float* __restrict__ a,
    const float* __restrict__ B, const float* __restrict__ b,
    float* __restrict__ out, int n_nodes, int gw, int tw, int lane)
{
    float wA[D], wB[D];
    #pragma unroll
    for (int k = 0; k < D; ++k) wA[k] = A[k * D + lane];
    #pragma unroll
    for (int k = 0; k < D; ++k) wB[k] = B[k * D + lane];
    const float ba = a[lane], bb = b[lane];

    int n = gw;
    if (n >= n_nodes) return;
    float v = x[(size_t)n * D + lane];

    for (; n < n_nodes; n += tw) {
        const int nn = n + tw;
        float vnext = 0.f;
        if (nn < n_nodes) vnext = x[(size_t)nn * D + lane];

        float h = ba;
        #pragma unroll
        for (int k = 0; k < D; ++k) h = fmaf(lane_bcast_f(v, k), wA[k], h);
        h = fmaxf(h, 0.f);

        float o = bb;
        #pragma unroll
        for (int k = 0; k < D; ++k) o = fmaf(lane_bcast_f(h, k), wB[k], o);
        o = fmaxf(o, 0.f);

        out[(size_t)n * D + lane] = o;
        v = vnext;
    }
}

// ---------------------------------------------------------------------------
// Phase 1 (fused): blocks [0, MLP_BLOCKS) run the message MLP; the rest run
// the dst histogram. Independent work overlapped in one launch.
// ---------------------------------------------------------------------------
__global__ __launch_bounds__(256) void phase1_kernel(
    const float* __restrict__ y,
    const float* __restrict__ W1, const float* __restrict__ b1,
    const float* __restrict__ W2, const float* __restrict__ b2,
    float* __restrict__ msg, int n_nodes,
    const int* __restrict__ dst, int* __restrict__ counts, int n_edges)
{
    if (blockIdx.x < MLP_BLOCKS) {
        const int lane = threadIdx.x & 63;
        const int wave = threadIdx.x >> 6;
        const int gw = blockIdx.x * 4 + wave;
        const int tw = MLP_BLOCKS * 4;
        mlp2_body(y, W1, b1, W2, b2, msg, n_nodes, gw, tw, lane);
    } else {
        int i = (blockIdx.x - MLP_BLOCKS) * 256 + threadIdx.x;
        if (i < n_edges) atomicAdd(&counts[dst[i]], 1);
    }
}

// ---------------------------------------------------------------------------
// Scan phase A: per-block (256-elem chunk) sums of counts
// ---------------------------------------------------------------------------
__global__ __launch_bounds__(256) void scanA_kernel(
    const int* __restrict__ counts, int* __restrict__ bsum, int n)
{
    __shared__ int red[4];
    int i = blockIdx.x * 256 + threadIdx.x;
    int v = (i < n) ? counts[i] : 0;
    #pragma unroll
    for (int off = 32; off > 0; off >>= 1) v += __shfl_down(v, off, 64);
    if ((threadIdx.x & 63) == 0) red[threadIdx.x >> 6] = v;
    __syncthreads();
    if (threadIdx.x == 0) bsum[blockIdx.x] = red[0] + red[1] + red[2] + red[3];
}

// ---------------------------------------------------------------------------
// Scan phase C (with block-sum scan fused): every block scans the <=256
// block sums in LDS, takes its exclusive base, then scans its own chunk.
// ---------------------------------------------------------------------------
__global__ __launch_bounds__(256) void scanC_kernel(
    const int* __restrict__ counts, const int* __restrict__ bsum,
    int* __restrict__ offsets, int* __restrict__ cursor,
    int n, int n_edges, int nb)
{
    __shared__ int btmp[256];
    __shared__ int tmp[256];
    const int t = threadIdx.x;

    // scan block sums (inclusive) in LDS
    int bx = (t < nb) ? bsum[t] : 0;
    btmp[t] = bx;
    __syncthreads();
    #pragma unroll
    for (int off = 1; off < 256; off <<= 1) {
        int add = (t >= off) ? btmp[t - off] : 0;
        __syncthreads();
        bx += add;
        btmp[t] = bx;
        __syncthreads();
    }
    const int base = (blockIdx.x == 0) ? 0 : btmp[blockIdx.x - 1];

    // scan own 256-chunk of counts
    const int i = blockIdx.x * 256 + t;
    int v = (i < n) ? counts[i] : 0;
    int x = v;
    tmp[t] = x;
    __syncthreads();
    #pragma unroll
    for (int off = 1; off < 256; off <<= 1) {
        int add = (t >= off) ? tmp[t - off] : 0;
        __syncthreads();
        x += add;
        tmp[t] = x;
        __syncthreads();
    }
    int excl = x - v + base;
    if (i < n) { offsets[i] = excl; cursor[i] = excl; }
    if (blockIdx.x == 0 && t == 0) offsets[n] = n_edges;
}

// ---------------------------------------------------------------------------
// CSR build: scatter src into dst-sorted order
// ---------------------------------------------------------------------------
__global__ __launch_bounds__(256) void perm_kernel(
    const int* __restrict__ src, const int* __restrict__ dst,
    int* __restrict__ cursor, int* __restrict__ sorted_src, int n_edges)
{
    int i = blockIdx.x * blockDim.x + threadIdx.x;
    if (i < n_edges) {
        int p = atomicAdd(&cursor[dst[i]], 1);
        sorted_src[p] = src[i];
    }
}

// ---------------------------------------------------------------------------
// Fused gather segment-sum + 2-layer MLP.
// Gather layout: lane = (grp, sub); grp = lane>>4 picks one of 4 edges per
// quad-step, sub = lane&15 picks 16B of the 256B row (float4). One load
// instruction fetches 4 full rows. Cross-group reduce via shfl_xor.
// ---------------------------------------------------------------------------
__global__ __launch_bounds__(256) void gather_mlp_kernel(
    const float* __restrict__ msg,
    const int* __restrict__ offsets, const int* __restrict__ sorted_src,
    const float* __restrict__ A, const float* __restrict__ a,
    const float* __restrict__ B, const float* __restrict__ b,
    float* __restrict__ out, int n_nodes)
{
    const int lane = threadIdx.x & 63;
    const int sub = lane & 15;
    const int grp = lane >> 4;
    const int wave = threadIdx.x >> 6;
    const int gw = blockIdx.x * (blockDim.x >> 6) + wave;
    const int tw = gridDim.x * (blockDim.x >> 6);

    float wA[D], wB[D];
    #pragma unroll
    for (int k = 0; k < D; ++k) wA[k] = A[k * D + lane];
    #pragma unroll
    for (int k = 0; k < D; ++k) wB[k] = B[k * D + lane];
    const float ba = a[lane], bb = b[lane];

    const float* msub = msg + (sub << 2);   // this lane's 16B slice of any row

    for (int n = gw; n < n_nodes; n += tw) {
        const int beg = offsets[n];
        const int end = offsets[n + 1];

        float4 acc0 = {0.f,0.f,0.f,0.f}, acc1 = {0.f,0.f,0.f,0.f};
        float4 acc2 = {0.f,0.f,0.f,0.f}, acc3 = {0.f,0.f,0.f,0.f};

        for (int base = beg; base < end; base += 64) {
            const int m = min(64, end - base);
            int idx = 0;
            if (lane < m) idx = sorted_src[base + lane];  // one coalesced load

            const int full = m >> 2;      // full quad-steps
            int j = 0;
            for (; j + 4 <= full; j += 4) {   // 4 loads in flight = 16 edges
                int e = (j << 2) + grp;
                int s0 = __shfl(idx, e,      64);
                int s1 = __shfl(idx, e + 4,  64);
                int s2 = __shfl(idx, e + 8,  64);
                int s3 = __shfl(idx, e + 12, 64);
                float4 v0 = *(const float4*)(msub + (size_t)s0 * D);
                float4 v1 = *(const float4*)(msub + (size_t)s1 * D);
                float4 v2 = *(const float4*)(msub + (size_t)s2 * D);
                float4 v3 = *(const float4*)(msub + (size_t)s3 * D);
                acc0.x += v0.x; acc0.y += v0.y; acc0.z += v0.z; acc0.w += v0.w;
                acc1.x += v1.x; acc1.y += v1.y; acc1.z += v1.z; acc1.w += v1.w;
                acc2.x += v2.x; acc2.y += v2.y; acc2.z += v2.z; acc2.w += v2.w;
                acc3.x += v3.x; acc3.y += v3.y; acc3.z += v3.z; acc3.w += v3.w;
            }
            for (; j < full; ++j) {
                int s = __shfl(idx, (j << 2) + grp, 64);
                float4 v = *(const float4*)(msub + (size_t)s * D);
                acc0.x += v.x; acc0.y += v.y; acc0.z += v.z; acc0.w += v.w;
            }
            const int rem = m & 3;
            if (rem) {
                // lanes with e >= m shuffled from lanes holding idx==0 -> safe
                int s = __shfl(idx, (full << 2) + grp, 64);
                float msk = (grp < rem) ? 1.f : 0.f;
                float4 v = *(const float4*)(msub + (size_t)s * D);
                acc0.x += v.x * msk; acc0.y += v.y * msk;
                acc0.z += v.z * msk; acc0.w += v.w * msk;
            }
        }

        // combine in-flight accumulators
        acc0.x += acc1.x + acc2.x + acc3.x;
        acc0.y += acc1.y + acc2.y + acc3.y;
        acc0.z += acc1.z + acc2.z + acc3.z;
        acc0.w += acc1.w + acc2.w + acc3.w;

        // cross-group butterfly: every lane ends with full sums of its 4 cols
        acc0.x += __shfl_xor(acc0.x, 16, 64);
        acc0.y += __shfl_xor(acc0.y, 16, 64);
        acc0.z += __shfl_xor(acc0.z, 16, 64);
        acc0.w += __shfl_xor(acc0.w, 16, 64);
        acc0.x += __shfl_xor(acc0.x, 32, 64);
        acc0.y += __shfl_xor(acc0.y, 32, 64);
        acc0.z += __shfl_xor(acc0.z, 32, 64);
        acc0.w += __shfl_xor(acc0.w, 32, 64);
        // z[k] lives in lane k>>2, member k&3 (any group)

        float h = ba;
        #pragma unroll
        for (int k = 0; k < D; ++k) {
            float zk;
            if      ((k & 3) == 0) zk = lane_bcast_f(acc0.x, k >> 2);
            else if ((k & 3) == 1) zk = lane_bcast_f(acc0.y, k >> 2);
            else if ((k & 3) == 2) zk = lane_bcast_f(acc0.z, k >> 2);
            else                   zk = lane_bcast_f(acc0.w, k >> 2);
            h = fmaf(zk, wA[k], h);
        }
        h = fmaxf(h, 0.f);

        float o = bb;
        #pragma unroll
        for (int k = 0; k < D; ++k) o = fmaf(lane_bcast_f(h, k), wB[k], o);
        o = fmaxf(o, 0.f);

        out[(size_t)n * D + lane] = o;
    }
}

extern "C" void kernel_launch(void* const* d_in, const int* in_sizes, int n_in,
                              void* d_out, int out_size, void* d_ws, size_t ws_size,
                              hipStream_t stream) {
    const float* y  = (const float*)d_in[0];
    const int*  src = (const int*) d_in[1];
    const int*  dst = (const int*) d_in[2];
    const float* W1 = (const float*)d_in[3];
    const float* b1 = (const float*)d_in[4];
    const float* W2 = (const float*)d_in[5];
    const float* b2 = (const float*)d_in[6];
    const float* U1 = (const float*)d_in[7];
    const float* c1 = (const float*)d_in[8];
    const float* U2 = (const float*)d_in[9];
    const float* c2 = (const float*)d_in[10];

    const int N = in_sizes[0] / D;   // 50000
    const int E = in_sizes[1];       // 1250000

    float* msg        = (float*)d_ws;
    int*   sorted_src = (int*)(msg + (size_t)N * D);
    int*   counts     = sorted_src + E;
    int*   offsets    = counts + N;
    int*   cursor     = offsets + (N + 1);
    int*   bsum       = cursor + N;

    const int NB    = (N + 255) / 256;   // 196 scan blocks
    const int gridE = (E + 255) / 256;   // 4883 hist/perm blocks

    hipMemsetAsync(counts, 0, (size_t)N * sizeof(int), stream);

    // fused: message MLP (blocks 0..1023) + dst histogram (rest)
    phase1_kernel<<<MLP_BLOCKS + gridE, 256, 0, stream>>>(
        y, W1, b1, W2, b2, msg, N, dst, counts, E);

    scanA_kernel<<<NB, 256, 0, stream>>>(counts, bsum, N);
    scanC_kernel<<<NB, 256, 0, stream>>>(counts, bsum, offsets, cursor, N, E, NB);
    perm_kernel<<<gridE, 256, 0, stream>>>(src, dst, cursor, sorted_src, E);

    gather_mlp_kernel<<<3200, 256, 0, stream>>>(msg, offsets, sorted_src,
                                                U1, c1, U2, c2,
                                                (float*)d_out, N);
}

// Round 5
// 272.485 us; speedup vs baseline: 5.0468x; 1.2131x over previous
//
#include <hip/hip_runtime.h>

#define D 64
#define MLP_BLOCKS 1024
#define CHUNK 4096      // edges per partition block
#define BSHIFT 8        // bucket = dst >> 8  (256 nodes per bucket)

typedef unsigned int uint;
typedef unsigned short ushort;

__device__ __forceinline__ float lane_bcast_f(float v, int k) {
    return __int_as_float(__builtin_amdgcn_readlane(__float_as_int(v), k));
}

// fp32 -> bf16 round-to-nearest-even (inputs are post-relu finite)
__device__ __forceinline__ ushort f2bf(float f) {
    uint u = __float_as_uint(f);
    return (ushort)((u + 0x7fffu + ((u >> 16) & 1u)) >> 16);
}

// decode a uint4 (8 packed bf16) and accumulate into even/odd fp32 accs
#define ACC8(v, aE, aO) do {                                                   \
    aE[0] += __uint_as_float((v).x << 16);                                     \
    aO[0] += __uint_as_float((v).x & 0xffff0000u);                             \
    aE[1] += __uint_as_float((v).y << 16);                                     \
    aO[1] += __uint_as_float((v).y & 0xffff0000u);                             \
    aE[2] += __uint_as_float((v).z << 16);                                     \
    aO[2] += __uint_as_float((v).z & 0xffff0000u);                             \
    aE[3] += __uint_as_float((v).w << 16);                                     \
    aO[3] += __uint_as_float((v).w & 0xffff0000u);                             \
} while (0)

// ---------------------------------------------------------------------------
// K1: blocks [0,NBA): per-chunk bucket histogram + global per-node histogram.
//     blocks [NBA, NBA+MLP_BLOCKS): message MLP, msg stored as bf16.
//     Block NBA also zeroes msg row N (the pad target row).
// ---------------------------------------------------------------------------
__global__ __launch_bounds__(256) void k1_mlp_hist(
    const float* __restrict__ y,
    const float* __restrict__ W1, const float* __restrict__ b1,
    const float* __restrict__ W2, const float* __restrict__ b2,
    ushort* __restrict__ msg16, int N,
    const int* __restrict__ dst, int* __restrict__ counts,
    int* __restrict__ histG, int E, int NBA)
{
    __shared__ int lhist[256];
    if ((int)blockIdx.x < NBA) {
        const int t = threadIdx.x;
        lhist[t] = 0;
        __syncthreads();
        const int cbase = blockIdx.x * CHUNK;
        for (int j = t; j < CHUNK; j += 256) {
            int e = cbase + j;
            if (e < E) {
                int d = dst[e];
                atomicAdd(&lhist[d >> BSHIFT], 1);
                atomicAdd(&counts[d], 1);
            }
        }
        __syncthreads();
        histG[blockIdx.x * 256 + t] = lhist[t];
    } else {
        const int blk = blockIdx.x - NBA;
        const int lane = threadIdx.x & 63;
        const int wave = threadIdx.x >> 6;
        if (blk == 0 && threadIdx.x < D) msg16[(size_t)N * D + threadIdx.x] = 0;

        float wA[D], wB[D];
        #pragma unroll
        for (int k = 0; k < D; ++k) wA[k] = W1[k * D + lane];
        #pragma unroll
        for (int k = 0; k < D; ++k) wB[k] = W2[k * D + lane];
        const float ba = b1[lane], bb = b2[lane];

        const int gw = blk * 4 + wave;
        const int tw = MLP_BLOCKS * 4;
        for (int n = gw; n < N; n += tw) {
            float v = y[(size_t)n * D + lane];
            float h = ba;
            #pragma unroll
            for (int k = 0; k < D; ++k) h = fmaf(lane_bcast_f(v, k), wA[k], h);
            h = fmaxf(h, 0.f);
            float o = bb;
            #pragma unroll
            for (int k = 0; k < D; ++k) o = fmaf(lane_bcast_f(h, k), wB[k], o);
            o = fmaxf(o, 0.f);
            msg16[(size_t)n * D + lane] = f2bf(o);
        }
    }
}

// ---------------------------------------------------------------------------
// K2: blocks [0,256): per-bucket scan over the NBA chunk histograms
//       -> startG[(chunk,bucket)] (excl within bucket) and tot[bucket].
//     blocks [256,256+NBpad): per-chunk sums of PADDED node counts -> bsumP.
// ---------------------------------------------------------------------------
__global__ __launch_bounds__(256) void k2_scans(
    const int* __restrict__ histG, int* __restrict__ startG,
    int* __restrict__ tot,
    const int* __restrict__ counts, int* __restrict__ bsumP,
    int N, int NBA)
{
    __shared__ int tmp[256];
    const int t = threadIdx.x;
    if (blockIdx.x < 256) {
        const int b = blockIdx.x;
        const int i0 = 2 * t, i1 = 2 * t + 1;
        int v0 = (i0 < NBA) ? histG[i0 * 256 + b] : 0;
        int v1 = (i1 < NBA) ? histG[i1 * 256 + b] : 0;
        int s = v0 + v1;
        int x = s; tmp[t] = x; __syncthreads();
        #pragma unroll
        for (int off = 1; off < 256; off <<= 1) {
            int add = (t >= off) ? tmp[t - off] : 0; __syncthreads();
            x += add; tmp[t] = x; __syncthreads();
        }
        int excl = x - s;
        if (i0 < NBA) startG[i0 * 256 + b] = excl;
        if (i1 < NBA) startG[i1 * 256 + b] = excl + v0;
        if (t == 255) tot[b] = x;
    } else {
        const int blk = blockIdx.x - 256;
        int i = blk * 256 + t;
        int c = (i < N) ? counts[i] : 0;
        int p = (c + 7) & ~7;   // padded to multiple of 8
        #pragma unroll
        for (int off = 32; off > 0; off >>= 1) p += __shfl_down(p, off, 64);
        if ((t & 63) == 0) tmp[t >> 6] = p;
        __syncthreads();
        if (t == 0) bsumP[blk] = tmp[0] + tmp[1] + tmp[2] + tmp[3];
    }
}

// ---------------------------------------------------------------------------
// K3: blocks [0,NBpad): padded exclusive scan -> offsets[] (+offsets[N]).
//     blocks [NBpad, NBpad+NBA): partition edges into bucket-grouped packedG
//     at per-(chunk,bucket) contiguous runs (coalesced-ish writes).
// ---------------------------------------------------------------------------
__global__ __launch_bounds__(256) void k3_offsets_scatter(
    const int* __restrict__ counts, const int* __restrict__ bsumP,
    int* __restrict__ offsets, int N, int E, int NBpad,
    const int* __restrict__ src, const int* __restrict__ dst,
    const int* __restrict__ startG, const int* __restrict__ tot,
    uint* __restrict__ packedG)
{
    __shared__ int t1[256];
    __shared__ int t2[256];
    const int t = threadIdx.x;
    if ((int)blockIdx.x < NBpad) {
        // inclusive scan of bsumP in t1
        int bx = (t < NBpad) ? bsumP[t] : 0;
        int x1 = bx; t1[t] = x1; __syncthreads();
        #pragma unroll
        for (int off = 1; off < 256; off <<= 1) {
            int add = (t >= off) ? t1[t - off] : 0; __syncthreads();
            x1 += add; t1[t] = x1; __syncthreads();
        }
        const int base = (blockIdx.x == 0) ? 0 : t1[blockIdx.x - 1];
        // scan own padded-count chunk
        const int i = blockIdx.x * 256 + t;
        int c = (i < N) ? counts[i] : 0;
        int p = (c + 7) & ~7;
        int x2 = p; t2[t] = x2; __syncthreads();
        #pragma unroll
        for (int off = 1; off < 256; off <<= 1) {
            int add = (t >= off) ? t2[t - off] : 0; __syncthreads();
            x2 += add; t2[t] = x2; __syncthreads();
        }
        int excl = x2 - p + base;
        if (i < N) offsets[i] = excl;
        if (blockIdx.x == 0 && t == 0) offsets[N] = t1[NBpad - 1];
    } else {
        const int blk = blockIdx.x - NBpad;
        // bucket bases from tot scan
        int tv = tot[t];
        int x = tv; t1[t] = x; __syncthreads();
        #pragma unroll
        for (int off = 1; off < 256; off <<= 1) {
            int add = (t >= off) ? t1[t - off] : 0; __syncthreads();
            x += add; t1[t] = x; __syncthreads();
        }
        t2[t] = (x - tv) + startG[blk * 256 + t];   // cursor per bucket
        __syncthreads();
        const int cbase = blk * CHUNK;
        for (int j = t; j < CHUNK; j += 256) {
            int e = cbase + j;
            if (e < E) {
                int s = src[e], d = dst[e];
                int pos = atomicAdd(&t2[d >> BSHIFT], 1);
                packedG[pos] = ((uint)(d & 255) << 16) | (uint)s;
            }
        }
    }
}

// ---------------------------------------------------------------------------
// K4: one block per bucket: scatter its packed entries to final padded
// positions (single-writer region -> L2 merges the 2B writes), then fill
// padding with the zero-row index N.
// ---------------------------------------------------------------------------
__global__ __launch_bounds__(256) void k4_place(
    const uint* __restrict__ packedG, const int* __restrict__ tot,
    const int* __restrict__ offsets,
    ushort* __restrict__ sortedG, int N)
{
    __shared__ int t1[256];
    __shared__ int sbase[256];
    __shared__ int cur[256];
    __shared__ int nxt[256];
    const int t = threadIdx.x;
    const int b = blockIdx.x;

    int tv = tot[t];
    int x = tv; t1[t] = x; __syncthreads();
    #pragma unroll
    for (int off = 1; off < 256; off <<= 1) {
        int add = (t >= off) ? t1[t - off] : 0; __syncthreads();
        x += add; t1[t] = x; __syncthreads();
    }
    sbase[t] = x - tv;
    const int node = b * 256 + t;
    cur[t] = (node < N) ? offsets[node] : 0;
    nxt[t] = (node < N) ? offsets[node + 1] : 0;
    __syncthreads();

    const int base_pk = sbase[b];
    const int cnt = tot[b];
    for (int i = t; i < cnt; i += 256) {
        uint e = packedG[base_pk + i];
        int dloc = e >> 16;
        int p = atomicAdd(&cur[dloc], 1);
        sortedG[p] = (ushort)(e & 0xffffu);
    }
    __syncthreads();
    if (node < N) {
        const ushort zr = (ushort)N;
        for (int p = cur[t]; p < nxt[t]; ++p) sortedG[p] = zr;  // <=7 pads
    }
}

// ---------------------------------------------------------------------------
// K5: fused gather segment-sum (bf16 msg, padded CSR) + update MLP.
// lane = (grp, sub): grp=lane>>3 picks one of 8 edges per step, sub=lane&7
// picks 16B (8 bf16) of the 128B row. One load = 8 full rows.
// ---------------------------------------------------------------------------
__global__ __launch_bounds__(256) void k5_gather_mlp(
    const ushort* __restrict__ msg16,
    const int* __restrict__ offsets, const ushort* __restrict__ sortedG,
    const float* __restrict__ A, const float* __restrict__ a,
    const float* __restrict__ B, const float* __restrict__ b,
    float* __restrict__ out, int n_nodes)
{
    const int lane = threadIdx.x & 63;
    const int sub = lane & 7;
    const int grp = lane >> 3;
    const int wave = threadIdx.x >> 6;
    const int gw = blockIdx.x * (blockDim.x >> 6) + wave;
    const int tw = gridDim.x * (blockDim.x >> 6);

    float wA[D], wB[D];
    #pragma unroll
    for (int k = 0; k < D; ++k) wA[k] = A[k * D + lane];
    #pragma unroll
    for (int k = 0; k < D; ++k) wB[k] = B[k * D + lane];
    const float ba = a[lane], bb = b[lane];

    const ushort* mbase = msg16 + (sub << 3);   // lane's 16B slice of any row

    for (int n = gw; n < n_nodes; n += tw) {
        const int beg = offsets[n];
        const int end = offsets[n + 1];   // end-beg is a multiple of 8

        float aE0[4] = {0,0,0,0}, aO0[4] = {0,0,0,0};
        float aE1[4] = {0,0,0,0}, aO1[4] = {0,0,0,0};

        for (int base = beg; base < end; base += 64) {
            const int m = min(64, end - base);
            int idx = 0;
            if (lane < m) idx = (int)sortedG[base + lane];
            const int full = m >> 3;    // exact: m is a multiple of 8
            int j = 0;
            for (; j + 4 <= full; j += 4) {
                int s0 = __shfl(idx, j * 8      + grp, 64);
                int s1 = __shfl(idx, j * 8 + 8  + grp, 64);
                int s2 = __shfl(idx, j * 8 + 16 + grp, 64);
                int s3 = __shfl(idx, j * 8 + 24 + grp, 64);
                uint4 v0 = *(const uint4*)(mbase + ((size_t)s0 << 6));
                uint4 v1 = *(const uint4*)(mbase + ((size_t)s1 << 6));
                uint4 v2 = *(const uint4*)(mbase + ((size_t)s2 << 6));
                uint4 v3 = *(const uint4*)(mbase + ((size_t)s3 << 6));
                ACC8(v0, aE0, aO0); ACC8(v1, aE1, aO1);
                ACC8(v2, aE0, aO0); ACC8(v3, aE1, aO1);
            }
            for (; j < full; ++j) {
                int s = __shfl(idx, j * 8 + grp, 64);
                uint4 v = *(const uint4*)(mbase + ((size_t)s << 6));
                ACC8(v, aE0, aO0);
            }
        }

        #pragma unroll
        for (int d2 = 0; d2 < 4; ++d2) {
            aE0[d2] += aE1[d2];
            aO0[d2] += aO1[d2];
            aE0[d2] += __shfl_xor(aE0[d2], 8, 64);
            aO0[d2] += __shfl_xor(aO0[d2], 8, 64);
            aE0[d2] += __shfl_xor(aE0[d2], 16, 64);
            aO0[d2] += __shfl_xor(aO0[d2], 16, 64);
            aE0[d2] += __shfl_xor(aE0[d2], 32, 64);
            aO0[d2] += __shfl_xor(aO0[d2], 32, 64);
        }
        // z[k] lives in lanes with sub==k>>3 (use grp0: lane k>>3),
        // member: parity (k&1) selects E/O, (k&7)>>1 selects the dword.

        float h = ba;
        #pragma unroll
        for (int k = 0; k < D; ++k) {
            const int srcLane = k >> 3;
            const int d2 = (k & 7) >> 1;
            float zk = ((k & 1) == 0) ? lane_bcast_f(aE0[d2], srcLane)
                                      : lane_bcast_f(aO0[d2], srcLane);
            h = fmaf(zk, wA[k], h);
        }
        h = fmaxf(h, 0.f);

        float o = bb;
        #pragma unroll
        for (int k = 0; k < D; ++k) o = fmaf(lane_bcast_f(h, k), wB[k], o);
        o = fmaxf(o, 0.f);

        out[(size_t)n * D + lane] = o;
    }
}

extern "C" void kernel_launch(void* const* d_in, const int* in_sizes, int n_in,
                              void* d_out, int out_size, void* d_ws, size_t ws_size,
                              hipStream_t stream) {
    const float* y  = (const float*)d_in[0];
    const int*  src = (const int*) d_in[1];
    const int*  dst = (const int*) d_in[2];
    const float* W1 = (const float*)d_in[3];
    const float* b1 = (const float*)d_in[4];
    const float* W2 = (const float*)d_in[5];
    const float* b2 = (const float*)d_in[6];
    const float* U1 = (const float*)d_in[7];
    const float* c1 = (const float*)d_in[8];
    const float* U2 = (const float*)d_in[9];
    const float* c2 = (const float*)d_in[10];

    const int N = in_sizes[0] / D;           // 50000
    const int E = in_sizes[1];               // 1250000
    const int NBA   = (E + CHUNK - 1) / CHUNK;   // 306 partition chunks
    const int NBpad = (N + 255) / 256;           // 196 node chunks == buckets

    // Workspace layout
    char* ws = (char*)d_ws;
    ushort* msg16 = (ushort*)ws;  ws += ((size_t)(N + 1) * D * 2 + 15) & ~15ull;
    int* counts   = (int*)ws;     ws += (size_t)N * 4;
    int* offsets  = (int*)ws;     ws += (size_t)(N + 1) * 4;
    int* histG    = (int*)ws;     ws += (size_t)NBA * 256 * 4;
    int* startG   = (int*)ws;     ws += (size_t)NBA * 256 * 4;
    int* tot      = (int*)ws;     ws += 256 * 4;
    int* bsumP    = (int*)ws;     ws += (size_t)((NBpad + 3) & ~3) * 4;
    uint* packedG = (uint*)ws;    ws += (size_t)E * 4;
    ushort* sortedG = (ushort*)ws;   // (E + 8N) ushorts

    hipMemsetAsync(counts, 0, (size_t)N * sizeof(int), stream);

    k1_mlp_hist<<<NBA + MLP_BLOCKS, 256, 0, stream>>>(
        y, W1, b1, W2, b2, msg16, N, dst, counts, histG, E, NBA);

    k2_scans<<<256 + NBpad, 256, 0, stream>>>(
        histG, startG, tot, counts, bsumP, N, NBA);

    k3_offsets_scatter<<<NBpad + NBA, 256, 0, stream>>>(
        counts, bsumP, offsets, N, E, NBpad, src, dst, startG, tot, packedG);

    k4_place<<<NBpad, 256, 0, stream>>>(packedG, tot, offsets, sortedG, N);

    k5_gather_mlp<<<3200, 256, 0, stream>>>(
        msg16, offsets, sortedG, U1, c1, U2, c2, (float*)d_out, N);
}